// Round 2
// baseline (875.286 us; speedup 1.0000x reference)
//
#include <hip/hip_runtime.h>
#include <hip/hip_bf16.h>
#include <stdint.h>

// EntityAttentionLayer: BS=1024, NE=128, IN=512, EMBED=512, NH=8, NA=32, HD=64
// k0: W f32->bf16
// kq: Q = E[:, :32] @ Wq^T * 0.125 -> q_ws bf16 [b][h][a][d]
// k1: per (b, head-pair): KV = E @ [Wk;Wv]^T (128x256) + attention -> attn bf16
// k2: out = attn @ W_out^T + b_out, post-mask

typedef __attribute__((ext_vector_type(8))) __bf16 bf16x8;
typedef __attribute__((ext_vector_type(4))) float f32x4;

static __device__ __forceinline__ unsigned short bfu(float x) {
  __hip_bfloat16 h = __float2bfloat16(x);
  union { __hip_bfloat16 h1; unsigned short u; } c; c.h1 = h; return c.u;
}
static __device__ __forceinline__ unsigned int pack2(float x, float y) {
  return (unsigned int)bfu(x) | ((unsigned int)bfu(y) << 16);
}
static __device__ __forceinline__ void gload16(const void* g, const void* l) {
  __builtin_amdgcn_global_load_lds(
      (const __attribute__((address_space(1))) unsigned int*)g,
      (__attribute__((address_space(3))) unsigned int*)l, 16, 0, 0);
}

// ---------------- k0: weight conversion ----------------
__global__ __launch_bounds__(256)
void k0_convert(const float* __restrict__ win, const float* __restrict__ wout,
                unsigned short* __restrict__ wb) {
  int t = blockIdx.x * 256 + threadIdx.x;
  int i = t * 4;  // 1048576 elems: Win 786432 then Wout 262144
  float4 v;
  if (i < 786432) v = *(const float4*)(win + i);
  else            v = *(const float4*)(wout + (i - 786432));
  uint2 pk; pk.x = pack2(v.x, v.y); pk.y = pack2(v.z, v.w);
  *(uint2*)(wb + i) = pk;
}

// ---------------- kq: Q projection (M=32768, N=512, K=512) ----------------
__global__ __launch_bounds__(256, 3)
void kq_qproj(const float* __restrict__ ent, const unsigned short* __restrict__ wb,
              unsigned short* __restrict__ q_ws) {
  __shared__ union {
    struct { unsigned short a[128 * 64]; unsigned short b[128 * 64]; } st;  // 32 KB
    unsigned short rs[128 * 136];                                           // 34.8 KB
  } sh;
  const int tid = threadIdx.x, w = tid >> 6, l = tid & 63;
  const int n = blockIdx.x;
  const int sw = (n & 7) * 128 + (n >> 3);
  const int mt = sw >> 2, ntb = sw & 3;
  char* aB = (char*)sh.st.a;
  char* bB = (char*)sh.st.b;
  const int hi16 = (l >> 4) << 4;
  const int trow = tid >> 4, tc4 = tid & 15;

  f32x4 acc[2][8];
#pragma unroll
  for (int i = 0; i < 2; ++i)
#pragma unroll
    for (int j = 0; j < 8; ++j) acc[i][j] = (f32x4){0.f, 0.f, 0.f, 0.f};

  for (int kt = 0; kt < 8; ++kt) {
    __syncthreads();
#pragma unroll
    for (int i = 0; i < 8; ++i) {
      int row = trow + i * 16;
      int gr = mt * 128 + row;
      const float4 v = *(const float4*)(ent + (size_t)(gr >> 5) * 65536 + (gr & 31) * 512 + kt * 64 + tc4 * 4);
      uint2 pk; pk.x = pack2(v.x, v.y); pk.y = pack2(v.z, v.w);
      int x = (row * 128 + tc4 * 8) ^ ((row & 7) << 4);
      *(uint2*)(aB + x) = pk;
    }
#pragma unroll
    for (int i = 0; i < 4; ++i) {
      int c = w * 4 + i;
      int x = c * 1024 + l * 16;
      int y = x ^ (((x >> 7) & 7) << 4);
      int idx = y >> 1, r = idx >> 6, col = idx & 63;
      gload16(wb + (size_t)(ntb * 128 + r) * 512 + kt * 64 + col, bB + c * 1024);
    }
    __syncthreads();
#pragma unroll
    for (int ks = 0; ks < 2; ++ks) {
      bf16x8 af[2];
#pragma unroll
      for (int i = 0; i < 2; ++i) {
        int row = (w * 2 + i) * 16 + (l & 15);
        af[i] = *(const bf16x8*)(aB + ((row * 128 + ks * 64 + hi16) ^ ((row & 7) << 4)));
      }
#pragma unroll
      for (int j = 0; j < 8; ++j) {
        int r = j * 16 + (l & 15);
        bf16x8 bf = *(const bf16x8*)(bB + ((r * 128 + ks * 64 + hi16) ^ ((r & 7) << 4)));
        acc[0][j] = __builtin_amdgcn_mfma_f32_16x16x32_bf16(af[0], bf, acc[0][j], 0, 0, 0);
        acc[1][j] = __builtin_amdgcn_mfma_f32_16x16x32_bf16(af[1], bf, acc[1][j], 0, 0, 0);
      }
    }
  }
  __syncthreads();
  // restage scaled bf16 into LDS, then coalesced scatter to q_ws[b][h][a][d]
#pragma unroll
  for (int i = 0; i < 2; ++i) {
    int row0 = w * 32 + i * 16 + (l >> 4) * 4;
#pragma unroll
    for (int j = 0; j < 8; ++j) {
      int col = j * 16 + (l & 15);
#pragma unroll
      for (int r = 0; r < 4; ++r) sh.rs[(row0 + r) * 136 + col] = bfu(acc[i][j][r] * 0.125f);
    }
  }
  __syncthreads();
#pragma unroll
  for (int it = 0; it < 8; ++it) {
    int row = it * 16 + (tid >> 4), c8 = (tid & 15) * 8;
    uint4 v = *(const uint4*)((const char*)sh.rs + row * 272 + c8 * 2);
    int gr = mt * 128 + row;
    int b = gr >> 5, a = gr & 31;
    int c = ntb * 128 + c8;
    int h = c >> 6, d = c & 63;
    *(uint4*)(q_ws + (((size_t)b * 8 + h) * 32 + a) * 64 + d) = v;
  }
}

// ---------------- k1: fused KV-projection + attention per (b, head-pair) ----------------
struct K1Lds {
  union {
    struct { unsigned short a[128 * 64]; unsigned short b[256 * 64]; } st;  // 49152 B
    struct {
      unsigned short kk[128 * 72];   // 18432 B  k  [e][d]  stride 144 B
      unsigned short vT[64 * 136];   // 17408 B  v^T [d][e] stride 272 B
      unsigned short qq[32 * 72];    //  4608 B  q/8 [a][d] stride 144 B
      float s[32 * 132];             // 16896 B  S   [a][e] stride 528 B
      unsigned short p[32 * 136];    //  8704 B  P   [a][e] stride 272 B
      unsigned short at[32 * 72];    //  4608 B  attn[a][d] stride 144 B
    } sm;                            // 70656 B total
  } u;
};

__global__ __launch_bounds__(512, 4)
void k1_fused(const float* __restrict__ ent, const int* __restrict__ pre,
              const unsigned short* __restrict__ wb, const unsigned short* __restrict__ q_ws,
              unsigned short* __restrict__ attn_out) {
  __shared__ K1Lds sh;
  const int tid = threadIdx.x;
  const int w = tid >> 6, l = tid & 63;
  const int n = blockIdx.x;
  const int xcd = n & 7, kid = n >> 3;
  const int b = xcd * 128 + (kid >> 2);  // all 4 head-pairs of a batch on one XCD
  const int h2 = kid & 3;

  const float* E = ent + (size_t)b * (128 * 512);
  char* aB = (char*)sh.u.st.a;
  char* bB = (char*)sh.u.st.b;
  const int hi16 = (l >> 4) << 4;
  const int wr = w >> 2;    // e-half (0..1)
  const int wq = w & 3;     // col quadrant: head=wq>>1, kv=wq&1

  f32x4 acc[4][4];
#pragma unroll
  for (int i = 0; i < 4; ++i)
#pragma unroll
    for (int j = 0; j < 4; ++j) acc[i][j] = (f32x4){0.f, 0.f, 0.f, 0.f};

  // ---- KV GEMM: C(128x256) = E(128x512) @ B^T, BK=64 ----
  for (int kt = 0; kt < 8; ++kt) {
    __syncthreads();
    // stage A: E f32 -> bf16, swizzled (512 threads, 4 rows-iters)
    {
      int col4 = tid & 15;
#pragma unroll
      for (int it = 0; it < 4; ++it) {
        int row = (tid >> 4) + it * 32;
        const float4 v = *(const float4*)(E + row * 512 + kt * 64 + col4 * 4);
        uint2 pk; pk.x = pack2(v.x, v.y); pk.y = pack2(v.z, v.w);
        int x = (row * 128 + col4 * 8) ^ ((row & 7) << 4);
        *(uint2*)(aB + x) = pk;
      }
    }
    // stage B: [k_h0|v_h0|k_h1|v_h1] rows, gload_lds with inverse-swizzled source
#pragma unroll
    for (int i = 0; i < 4; ++i) {
      int c = w * 4 + i;
      int x = c * 1024 + l * 16;
      int y = x ^ (((x >> 7) & 7) << 4);
      int idx = y >> 1, r = idx >> 6, col = idx & 63;
      int wrow = 512 + ((r >> 6) & 1) * 512 + (h2 * 2 + (r >> 7)) * 64 + (r & 63);
      gload16(wb + (size_t)wrow * 512 + kt * 64 + col, bB + c * 1024);
    }
    __syncthreads();
#pragma unroll
    for (int ks = 0; ks < 2; ++ks) {
      bf16x8 af[4], bf[4];
#pragma unroll
      for (int i = 0; i < 4; ++i) {
        int row = wr * 64 + i * 16 + (l & 15);
        af[i] = *(const bf16x8*)(aB + ((row * 128 + ks * 64 + hi16) ^ ((row & 7) << 4)));
      }
#pragma unroll
      for (int j = 0; j < 4; ++j) {
        int r = (wq * 4 + j) * 16 + (l & 15);
        bf[j] = *(const bf16x8*)(bB + ((r * 128 + ks * 64 + hi16) ^ ((r & 7) << 4)));
      }
#pragma unroll
      for (int i = 0; i < 4; ++i)
#pragma unroll
        for (int j = 0; j < 4; ++j)
          acc[i][j] = __builtin_amdgcn_mfma_f32_16x16x32_bf16(af[i], bf[j], acc[i][j], 0, 0, 0);
    }
  }
  __syncthreads();

  // ---- attention, heads sequential ----
  for (int h = 0; h < 2; ++h) {
    // scatter this head's K,V from acc; load q tile
    if ((wq >> 1) == h) {
      const int kv = wq & 1;
#pragma unroll
      for (int i = 0; i < 4; ++i) {
        int e0 = wr * 64 + i * 16 + (l >> 4) * 4;
#pragma unroll
        for (int j = 0; j < 4; ++j) {
          int d = j * 16 + (l & 15);
          if (kv == 0) {
#pragma unroll
            for (int r = 0; r < 4; ++r) sh.u.sm.kk[(e0 + r) * 72 + d] = bfu(acc[i][j][r]);
          } else {
            uint2 pk;
            pk.x = pack2(acc[i][j][0], acc[i][j][1]);
            pk.y = pack2(acc[i][j][2], acc[i][j][3]);
            *(uint2*)((char*)sh.u.sm.vT + d * 272 + e0 * 2) = pk;
          }
        }
      }
    }
    if (tid < 256) {
      int row = tid >> 3, c8 = (tid & 7) * 8;
      uint4 v = *(const uint4*)(q_ws + (((size_t)b * 8 + h2 * 2 + h) * 32 + row) * 64 + c8);
      *(uint4*)((char*)sh.u.sm.qq + row * 144 + c8 * 2) = v;
    }
    __syncthreads();

    // S = q @ k^T : wave -> a-tile (w>>2), e-tiles (w&3)*2 + {0,1}
    {
      f32x4 sacc[2] = {(f32x4){0.f, 0.f, 0.f, 0.f}, (f32x4){0.f, 0.f, 0.f, 0.f}};
      const int at = w >> 2;
#pragma unroll
      for (int ks = 0; ks < 2; ++ks) {
        int arow = at * 16 + (l & 15);
        bf16x8 qf = *(const bf16x8*)((char*)sh.u.sm.qq + arow * 144 + ks * 64 + hi16);
#pragma unroll
        for (int je = 0; je < 2; ++je) {
          int e = ((w & 3) * 2 + je) * 16 + (l & 15);
          bf16x8 kf = *(const bf16x8*)((char*)sh.u.sm.kk + e * 144 + ks * 64 + hi16);
          sacc[je] = __builtin_amdgcn_mfma_f32_16x16x32_bf16(qf, kf, sacc[je], 0, 0, 0);
        }
      }
#pragma unroll
      for (int je = 0; je < 2; ++je) {
        int e = ((w & 3) * 2 + je) * 16 + (l & 15);
        int a0 = at * 16 + (l >> 4) * 4;
#pragma unroll
        for (int r = 0; r < 4; ++r) sh.u.sm.s[(a0 + r) * 132 + e] = sacc[je][r];
      }
    }
    __syncthreads();

    // masked softmax over e (8 lanes per agent row), tid<256
    if (tid < 256) {
      int a = tid >> 3, ls = tid & 7;
      const int* pm = pre + ((size_t)b * 32 + a) * 128 + ls * 16;
      const float* srow = sh.u.sm.s + a * 132 + ls * 16;
      float sv[16]; int mk[16];
      float mx = -__builtin_inff();
#pragma unroll
      for (int c = 0; c < 4; ++c) {
        int4 m4 = *(const int4*)(pm + c * 4);
        float4 s4 = *(const float4*)(srow + c * 4);
        mk[c * 4 + 0] = m4.x; sv[c * 4 + 0] = s4.x;
        mk[c * 4 + 1] = m4.y; sv[c * 4 + 1] = s4.y;
        mk[c * 4 + 2] = m4.z; sv[c * 4 + 2] = s4.z;
        mk[c * 4 + 3] = m4.w; sv[c * 4 + 3] = s4.w;
      }
#pragma unroll
      for (int i = 0; i < 16; ++i)
        if (!mk[i]) mx = fmaxf(mx, sv[i]);
      mx = fmaxf(mx, __shfl_xor(mx, 1));
      mx = fmaxf(mx, __shfl_xor(mx, 2));
      mx = fmaxf(mx, __shfl_xor(mx, 4));
      const bool dead = (mx == -__builtin_inff());
      float pv[16]; float sum = 0.f;
#pragma unroll
      for (int i = 0; i < 16; ++i) {
        float p = (mk[i] || dead) ? 0.f : __expf(sv[i] - mx);
        pv[i] = p; sum += p;
      }
      sum += __shfl_xor(sum, 1);
      sum += __shfl_xor(sum, 2);
      sum += __shfl_xor(sum, 4);
      float inv = dead ? 0.f : (1.f / sum);
      unsigned short* P = sh.u.sm.p + a * 136 + ls * 16;
#pragma unroll
      for (int c = 0; c < 4; ++c) {
        uint2 pk;
        pk.x = pack2(pv[c * 4 + 0] * inv, pv[c * 4 + 1] * inv);
        pk.y = pack2(pv[c * 4 + 2] * inv, pv[c * 4 + 3] * inv);
        *(uint2*)(P + c * 4) = pk;
      }
    }
    __syncthreads();

    // attn = P @ v : wave -> a-tile (w>>2), d-tile (w&3)
    {
      const int at = w >> 2, dt = w & 3;
      f32x4 pacc = (f32x4){0.f, 0.f, 0.f, 0.f};
#pragma unroll
      for (int ks = 0; ks < 4; ++ks) {
        int arow = at * 16 + (l & 15);
        bf16x8 pf = *(const bf16x8*)((char*)sh.u.sm.p + arow * 272 + ks * 64 + hi16);
        int d = dt * 16 + (l & 15);
        bf16x8 vf = *(const bf16x8*)((char*)sh.u.sm.vT + d * 272 + ks * 64 + hi16);
        pacc = __builtin_amdgcn_mfma_f32_16x16x32_bf16(pf, vf, pacc, 0, 0, 0);
      }
      int d = dt * 16 + (l & 15);
      int a0 = at * 16 + (l >> 4) * 4;
#pragma unroll
      for (int r = 0; r < 4; ++r) sh.u.sm.at[(a0 + r) * 72 + d] = bfu(pacc[r]);
    }
    __syncthreads();

    // coalesced write of attn tile (32x64 bf16)
    if (tid < 256) {
      int row = tid >> 3, c8 = (tid & 7) * 8;
      uint4 v = *(const uint4*)((const char*)sh.u.sm.at + row * 144 + c8 * 2);
      *(uint4*)(attn_out + ((size_t)(b * 32 + row) * 512 + (h2 * 2 + h) * 64 + c8)) = v;
    }
    __syncthreads();
  }
}

// ---------------- k2: out = attn @ W_out^T + b_out, post-mask (256x128 tile) ----------------
__global__ __launch_bounds__(512, 4)
void k2_out(const unsigned short* __restrict__ attn, const unsigned short* __restrict__ wob,
            const float* __restrict__ bout, const int* __restrict__ post,
            float* __restrict__ out) {
  __shared__ struct { unsigned short a[256 * 64]; unsigned short b[128 * 64]; } sh;  // 48 KB
  const int tid = threadIdx.x, w = tid >> 6, l = tid & 63;
  const int n = blockIdx.x;
  const int sw = (n & 7) * 64 + (n >> 3);
  const int mt = sw >> 2, ntb = sw & 3;
  const int wr = w >> 1, wc = w & 1;
  char* aB = (char*)sh.a;
  char* bB = (char*)sh.b;
  const int hi16 = (l >> 4) << 4;

  f32x4 acc[4][4];
#pragma unroll
  for (int i = 0; i < 4; ++i)
#pragma unroll
    for (int j = 0; j < 4; ++j) acc[i][j] = (f32x4){0.f, 0.f, 0.f, 0.f};

  for (int kt = 0; kt < 8; ++kt) {
    __syncthreads();
#pragma unroll
    for (int i = 0; i < 4; ++i) {
      int c = w * 4 + i;
      int x = c * 1024 + l * 16;
      int y = x ^ (((x >> 7) & 7) << 4);
      int idx = y >> 1, r = idx >> 6, col = idx & 63;
      gload16(attn + (size_t)(mt * 256 + r) * 512 + kt * 64 + col, aB + c * 1024);
    }
#pragma unroll
    for (int i = 0; i < 2; ++i) {
      int c = w * 2 + i;
      int x = c * 1024 + l * 16;
      int y = x ^ (((x >> 7) & 7) << 4);
      int idx = y >> 1, r = idx >> 6, col = idx & 63;
      gload16(wob + (size_t)(ntb * 128 + r) * 512 + kt * 64 + col, bB + c * 1024);
    }
    __syncthreads();
#pragma unroll
    for (int ks = 0; ks < 2; ++ks) {
      bf16x8 af[4], bf[4];
#pragma unroll
      for (int i = 0; i < 4; ++i) {
        int row = wr * 64 + i * 16 + (l & 15);
        af[i] = *(const bf16x8*)(aB + ((row * 128 + ks * 64 + hi16) ^ ((row & 7) << 4)));
      }
#pragma unroll
      for (int j = 0; j < 4; ++j) {
        int r = wc * 64 + j * 16 + (l & 15);
        bf[j] = *(const bf16x8*)(bB + ((r * 128 + ks * 64 + hi16) ^ ((r & 7) << 4)));
      }
#pragma unroll
      for (int i = 0; i < 4; ++i)
#pragma unroll
        for (int j = 0; j < 4; ++j)
          acc[i][j] = __builtin_amdgcn_mfma_f32_16x16x32_bf16(af[i], bf[j], acc[i][j], 0, 0, 0);
    }
  }

  float bo[4];
#pragma unroll
  for (int j = 0; j < 4; ++j) bo[j] = bout[ntb * 128 + wc * 64 + j * 16 + (l & 15)];
#pragma unroll
  for (int i = 0; i < 4; ++i) {
    int m0 = mt * 256 + wr * 64 + i * 16 + (l >> 4) * 4;
    int pmv[4];
#pragma unroll
    for (int r = 0; r < 4; ++r) pmv[r] = post[m0 + r];
#pragma unroll
    for (int j = 0; j < 4; ++j) {
      int nn = ntb * 128 + wc * 64 + j * 16 + (l & 15);
#pragma unroll
      for (int r = 0; r < 4; ++r) {
        float v = pmv[r] ? 0.f : (acc[i][j][r] + bo[j]);
        out[(size_t)(m0 + r) * 512 + nn] = v;
      }
    }
  }
}

extern "C" void kernel_launch(void* const* d_in, const int* in_sizes, int n_in,
                              void* d_out, int out_size, void* d_ws, size_t ws_size,
                              hipStream_t stream) {
  const float* ent  = (const float*)d_in[0];
  const int*   pre  = (const int*)d_in[1];
  const int*   post = (const int*)d_in[2];
  const float* win  = (const float*)d_in[3];
  const float* wout = (const float*)d_in[4];
  const float* bout = (const float*)d_in[5];
  float* out = (float*)d_out;

  unsigned short* wsb   = (unsigned short*)d_ws;
  unsigned short* winb  = wsb;             // 786432 bf16
  unsigned short* woutb = wsb + 786432;    // 262144 bf16
  unsigned short* q_ws  = wsb + 1048576;   // 16777216 bf16 (33.5 MB)
  unsigned short* attnb = wsb + 17825792;  // 16777216 bf16 (33.5 MB)

  hipLaunchKernelGGL(k0_convert, dim3(1024), dim3(256), 0, stream, win, wout, wsb);
  hipLaunchKernelGGL(kq_qproj, dim3(1024), dim3(256), 0, stream, ent, winb, q_ws);
  hipLaunchKernelGGL(k1_fused, dim3(4096), dim3(512), 0, stream, ent, pre, winb, q_ws, attnb);
  hipLaunchKernelGGL(k2_out, dim3(512), dim3(512), 0, stream, attnb, woutb, bout, post, out);
}